// Round 16
// baseline (222.947 us; speedup 1.0000x reference)
//
#include <hip/hip_runtime.h>
#include <hip/hip_bf16.h>

#define CIN   64
#define COUT  128
#define TT    256
#define VV    25
#define TV    (TT * VV)   // 6400
#define KW    9
#define PAD   4
#define YROW  28          // padded bf16 y row: 56B
#define YSTR  (TT * YROW) // 7168 shorts per (n,c) plane

typedef __attribute__((ext_vector_type(8))) short short8;   // 8 bf16 (4 VGPRs)
typedef __attribute__((ext_vector_type(4))) float f32x4;

__device__ __forceinline__ unsigned f2b(float f) {          // fp32 -> bf16 bits (RNE)
    unsigned u = __builtin_bit_cast(unsigned, f);
    return (u + 0x7FFFu + ((u >> 16) & 1u)) >> 16;
}
__device__ __forceinline__ float lof(unsigned u) {          // low bf16 -> f32
    return __builtin_bit_cast(float, u << 16);
}
__device__ __forceinline__ float hif(unsigned u) {          // high bf16 -> f32
    return __builtin_bit_cast(float, u & 0xffff0000u);
}
// conv LDS tile swizzle: [row][128B], XOR slot with (row&7)
__device__ __forceinline__ int swz(int row, int cbyte) {
    return row * 128 + ((cbyte & ~15) ^ ((row & 7) << 4)) + (cbyte & 15);
}

// ---------------- Kernel A: 1x1 conv + BN via bf16 MFMA (unchanged) ----------------
__global__ __launch_bounds__(256) void conv_mfma(
    const float* __restrict__ x, const float* __restrict__ w,
    const float* __restrict__ cb, const float* __restrict__ gamma,
    const float* __restrict__ beta, const float* __restrict__ rm,
    const float* __restrict__ rv, unsigned short* __restrict__ y)
{
    __shared__ __align__(16) unsigned short Wl[COUT * 64];   // 16 KB, swizzled
    __shared__ __align__(16) unsigned short Xl[128 * 64];    // 16 KB, swizzled [pos][c]
    __shared__ float sc[COUT];
    __shared__ float of[COUT];

    const int pc  = blockIdx.x;       // 0..49
    const int n   = blockIdx.y;       // 0..15
    const int tid = threadIdx.x;
    const int posbase = pc * 128;

    if (tid < COUT) {
        const float s = gamma[tid] * rsqrtf(rv[tid] + 1e-5f);
        sc[tid] = s;
        of[tid] = cb[tid] * s + beta[tid] - rm[tid] * s;
    }
    for (int idx = tid; idx < 2048; idx += 256) {
        const int c4 = idx & 15, o = idx >> 4;
        const f32x4 wv = *(const f32x4*)(w + o * 64 + c4 * 4);
        uint2 pk;
        pk.x = f2b(wv.x) | (f2b(wv.y) << 16);
        pk.y = f2b(wv.z) | (f2b(wv.w) << 16);
        *(uint2*)((char*)Wl + swz(o, c4 * 8)) = pk;
    }
    for (int idx = tid; idx < 2048; idx += 256) {
        const int pos = idx & 127, c4 = idx >> 7;
        const float* xp = x + (size_t)n * CIN * TV + (size_t)(c4 * 4) * TV + posbase + pos;
        const float a0 = xp[0], a1 = xp[TV], a2 = xp[2 * TV], a3 = xp[3 * TV];
        uint2 pk;
        pk.x = f2b(a0) | (f2b(a1) << 16);
        pk.y = f2b(a2) | (f2b(a3) << 16);
        *(uint2*)((char*)Xl + swz(pos, c4 * 8)) = pk;
    }
    __syncthreads();

    const int wv_ = tid >> 6, lane = tid & 63;
    const int lr = lane & 15, lh = lane >> 4;   // lh in 0..3

    short8 afr[2][2];
#pragma unroll
    for (int m0 = 0; m0 < 2; ++m0)
#pragma unroll
        for (int kh = 0; kh < 2; ++kh)
            afr[m0][kh] = *(const short8*)((const char*)Wl +
                              swz(wv_ * 32 + m0 * 16 + lr, kh * 64 + lh * 16));

    f32x4 acc[2][8];
#pragma unroll
    for (int m0 = 0; m0 < 2; ++m0)
#pragma unroll
        for (int n0 = 0; n0 < 8; ++n0) acc[m0][n0] = (f32x4){0.f, 0.f, 0.f, 0.f};

#pragma unroll
    for (int n0 = 0; n0 < 8; ++n0) {
        const int prow = n0 * 16 + lr;
        const short8 b0 = *(const short8*)((const char*)Xl + swz(prow, lh * 16));
        const short8 b1 = *(const short8*)((const char*)Xl + swz(prow, 64 + lh * 16));
#pragma unroll
        for (int m0 = 0; m0 < 2; ++m0) {
            acc[m0][n0] = __builtin_amdgcn_mfma_f32_16x16x32_bf16(afr[m0][0], b0, acc[m0][n0], 0, 0, 0);
            acc[m0][n0] = __builtin_amdgcn_mfma_f32_16x16x32_bf16(afr[m0][1], b1, acc[m0][n0], 0, 0, 0);
        }
    }

    float scv[2][4], ofv[2][4];
#pragma unroll
    for (int m0 = 0; m0 < 2; ++m0)
#pragma unroll
        for (int r = 0; r < 4; ++r) {
            const int o = wv_ * 32 + m0 * 16 + lh * 4 + r;
            scv[m0][r] = sc[o];
            ofv[m0][r] = of[o];
        }

    const size_t ybase = (size_t)(n * COUT) * YSTR;
#pragma unroll
    for (int m0 = 0; m0 < 2; ++m0)
#pragma unroll
        for (int n0 = 0; n0 < 8; ++n0)
#pragma unroll
            for (int r = 0; r < 4; ++r) {
                const int o = wv_ * 32 + m0 * 16 + lh * 4 + r;
                const int pos = posbase + n0 * 16 + lr;
                const int t = pos / 25;
                const int v = pos - t * 25;
                const float val = acc[m0][n0][r] * scv[m0][r] + ofv[m0][r];
                y[ybase + (size_t)o * YSTR + t * YROW + v] = (unsigned short)f2b(val);
            }
}

// ---------------- Kernel B: temporal-window attention (R10 dataflow, low-VGPR) ----------------
// 2048 blocks x 256 threads, t = tid. LDS bf16 tile (R10: halo + linear stage,
// conflict-free: 14*l mod 32 sweeps all 16 evens). Change vs R10: all 9 rows'
// PACKED dwords (9 x 7 = 63 regs) are held in registers, read from LDS once;
// phase 1 computes the 9 exp scores (transient unpack), phase 2 does ONE
// accumulation with coef_j = e_j/den + att0_j. Same VALU count as R10
// (+225 unpack, -225 dual-accum FMA), but peak live state ~120 regs ->
// __launch_bounds__(256,4) (4 waves/EU, VGPR<=128) without spilling.

// unpack packed row regs (named a,b,c,d) and FMA into two partial dots vs q
#define DOTROW(ra, rb, rc, rd, d0, d1)                                      \
    {                                                                       \
        d0 = fmaf(lof(ra.x), q[0], d0);  d0 = fmaf(hif(ra.x), q[1], d0);    \
        d0 = fmaf(lof(ra.y), q[2], d0);  d0 = fmaf(hif(ra.y), q[3], d0);    \
        d1 = fmaf(lof(rb.x), q[4], d1);  d1 = fmaf(hif(rb.x), q[5], d1);    \
        d1 = fmaf(lof(rb.y), q[6], d1);  d1 = fmaf(hif(rb.y), q[7], d1);    \
        d0 = fmaf(lof(rc.x), q[8], d0);  d0 = fmaf(hif(rc.x), q[9], d0);    \
        d0 = fmaf(lof(rc.y), q[10], d0); d0 = fmaf(hif(rc.y), q[11], d0);   \
        d1 = fmaf(lof(rd.x), q[12], d1); d1 = fmaf(hif(rd.x), q[13], d1);   \
        d1 = fmaf(lof(rd.y), q[14], d1); d1 = fmaf(hif(rd.y), q[15], d1);   \
        d0 = fmaf(lof(re.x), q[16], d0); d0 = fmaf(hif(re.x), q[17], d0);   \
        d0 = fmaf(lof(re.y), q[18], d0); d0 = fmaf(hif(re.y), q[19], d0);   \
        d1 = fmaf(lof(rf.x), q[20], d1); d1 = fmaf(hif(rf.x), q[21], d1);   \
        d1 = fmaf(lof(rf.y), q[22], d1); d1 = fmaf(hif(rf.y), q[23], d1);   \
        d0 = fmaf(lof(rg), q[24], d0);                                      \
    }

// accumulate coef * row into o[25] from packed regs
#define ACCROW(ra, rb, rc, rd, cf)                                          \
    {                                                                       \
        o[0]  = fmaf(lof(ra.x), cf, o[0]);  o[1]  = fmaf(hif(ra.x), cf, o[1]); \
        o[2]  = fmaf(lof(ra.y), cf, o[2]);  o[3]  = fmaf(hif(ra.y), cf, o[3]); \
        o[4]  = fmaf(lof(rb.x), cf, o[4]);  o[5]  = fmaf(hif(rb.x), cf, o[5]); \
        o[6]  = fmaf(lof(rb.y), cf, o[6]);  o[7]  = fmaf(hif(rb.y), cf, o[7]); \
        o[8]  = fmaf(lof(rc.x), cf, o[8]);  o[9]  = fmaf(hif(rc.x), cf, o[9]); \
        o[10] = fmaf(lof(rc.y), cf, o[10]); o[11] = fmaf(hif(rc.y), cf, o[11]);\
        o[12] = fmaf(lof(rd.x), cf, o[12]); o[13] = fmaf(hif(rd.x), cf, o[13]);\
        o[14] = fmaf(lof(rd.y), cf, o[14]); o[15] = fmaf(hif(rd.y), cf, o[15]);\
        o[16] = fmaf(lof(re.x), cf, o[16]); o[17] = fmaf(hif(re.x), cf, o[17]);\
        o[18] = fmaf(lof(re.y), cf, o[18]); o[19] = fmaf(hif(re.y), cf, o[19]);\
        o[20] = fmaf(lof(rf.x), cf, o[20]); o[21] = fmaf(hif(rf.x), cf, o[21]);\
        o[22] = fmaf(lof(rf.y), cf, o[22]); o[23] = fmaf(hif(rf.y), cf, o[23]);\
        o[24] = fmaf(lof(rg), cf, o[24]);                                   \
    }

#define ROWREGS(j) uint2 p##j##a, p##j##b, p##j##c, p##j##d, p##j##e, p##j##f; unsigned p##j##g
#define LOADP(j, rl)                                                        \
    {                                                                       \
        const int b2_ = (rl) * 7;                                           \
        p##j##a = tl2[b2_];     p##j##b = tl2[b2_ + 1];                     \
        p##j##c = tl2[b2_ + 2]; p##j##d = tl2[b2_ + 3];                     \
        p##j##e = tl2[b2_ + 4]; p##j##f = tl2[b2_ + 5];                     \
        p##j##g = tlu[14 * (rl) + 12];                                      \
    }
#define DOT_J(j, dd)                                                        \
    {                                                                       \
        float d0 = 0.f, d1 = 0.f;                                           \
        const uint2 re = p##j##e, rf = p##j##f; const unsigned rg = p##j##g;\
        DOTROW(p##j##a, p##j##b, p##j##c, p##j##d, d0, d1);                 \
        dd = (d0 + d1) * (1.f / 25.f);                                      \
    }
#define ACC_J(j, cf)                                                        \
    {                                                                       \
        const uint2 re = p##j##e, rf = p##j##f; const unsigned rg = p##j##g;\
        ACCROW(p##j##a, p##j##b, p##j##c, p##j##d, cf);                     \
    }

__global__ __launch_bounds__(256, 4) void attn_kernel(
    const unsigned short* __restrict__ y, const float* __restrict__ att0,
    float* __restrict__ out)
{
    __shared__ __align__(16) float sm[TV];   // 25.6 KB: bf16 tile (14.8KB), then fp32 overlay
    __shared__ float a0s[KW];

    uint4* tl4 = (uint4*)sm;                  // tile: 924 uint4 = 14784 B
    const uint2* tl2 = (const uint2*)sm;
    const unsigned* tlu = (const unsigned*)sm;

    const int nc  = blockIdx.x;       // n*COUT + c
    const int c   = nc & (COUT - 1);
    const int tid = threadIdx.x;

    if (tid < KW) a0s[tid] = att0[c * KW + tid];

    // zero halo: front uint4 [0,14) (rows -4..-1), back [910,924) (rows 256..259)
    if (tid < 28) {
        const int i = (tid < 14) ? tid : (896 + tid);
        tl4[i] = make_uint4(0, 0, 0, 0);
    }
    // stage: linear copy, 896 uint4, fully coalesced
    const uint4* yg = (const uint4*)(y + (size_t)nc * YSTR);
#pragma unroll
    for (int i = 0; i < 4; ++i) {
        const int ci = tid + i * 256;
        if (ci < 896) tl4[14 + ci] = yg[ci];
    }
    __syncthreads();

    const int t = tid;                // local rows t .. t+8; center = t+4

    // load all 9 rows packed (63 dwords), LDS read once per row
    ROWREGS(0); ROWREGS(1); ROWREGS(2); ROWREGS(3); ROWREGS(4);
    ROWREGS(5); ROWREGS(6); ROWREGS(7); ROWREGS(8);
    LOADP(0, t + 0); LOADP(1, t + 1); LOADP(2, t + 2); LOADP(3, t + 3);
    LOADP(4, t + 4); LOADP(5, t + 5); LOADP(6, t + 6); LOADP(7, t + 7);
    LOADP(8, t + 8);

    // unpack center row q once
    float q[25];
    {
        q[0]  = lof(p4a.x); q[1]  = hif(p4a.x); q[2]  = lof(p4a.y); q[3]  = hif(p4a.y);
        q[4]  = lof(p4b.x); q[5]  = hif(p4b.x); q[6]  = lof(p4b.y); q[7]  = hif(p4b.y);
        q[8]  = lof(p4c.x); q[9]  = hif(p4c.x); q[10] = lof(p4c.y); q[11] = hif(p4c.y);
        q[12] = lof(p4d.x); q[13] = hif(p4d.x); q[14] = lof(p4d.y); q[15] = hif(p4d.y);
        q[16] = lof(p4e.x); q[17] = hif(p4e.x); q[18] = lof(p4e.y); q[19] = hif(p4e.y);
        q[20] = lof(p4f.x); q[21] = hif(p4f.x); q[22] = lof(p4f.y); q[23] = hif(p4f.y);
        q[24] = lof(p4g);
    }

    // ---- phase 1: 9 scores ----
    float cf[KW];
    DOT_J(0, cf[0]); DOT_J(1, cf[1]); DOT_J(2, cf[2]); DOT_J(3, cf[3]);
    DOT_J(4, cf[4]); DOT_J(5, cf[5]); DOT_J(6, cf[6]); DOT_J(7, cf[7]);
    DOT_J(8, cf[8]);

    // softmax (no max-subtract: |s| <= ~40 << 88) + fold att0: ONE coefficient
    {
        float den = 0.f;
#pragma unroll
        for (int j = 0; j < KW; ++j) { cf[j] = __expf(cf[j]); den += cf[j]; }
        const float inv = 1.f / den;
#pragma unroll
        for (int j = 0; j < KW; ++j) cf[j] = fmaf(cf[j], inv, a0s[j]);
    }

    // ---- phase 2: single weighted accumulation from held packed rows ----
    float o[25];
#pragma unroll
    for (int v = 0; v < 25; ++v) o[v] = 0.f;
    ACC_J(0, cf[0]); ACC_J(1, cf[1]); ACC_J(2, cf[2]); ACC_J(3, cf[3]);
    ACC_J(4, cf[4]); ACC_J(5, cf[5]); ACC_J(6, cf[6]); ACC_J(7, cf[7]);
    ACC_J(8, cf[8]);

    // ---- overlay pack (scalar b32; lane stride 25 dwords, odd -> benign) ----
    __syncthreads();
    {
        float* dst = &sm[t * 25];
#pragma unroll
        for (int v = 0; v < 25; ++v) dst[v] = o[v];
    }
    __syncthreads();

    // ---- block-contiguous float4 stores: full 64B lines per instruction ----
    {
        float4* og = (float4*)(out + (size_t)nc * TV);
        const float4* sm4 = (const float4*)sm;
#pragma unroll
        for (int i = 0; i < 7; ++i) {
            const int ci = tid + i * 256;
            if (ci < TV / 4) og[ci] = sm4[ci];
        }
    }
}

extern "C" void kernel_launch(void* const* d_in, const int* in_sizes, int n_in,
                              void* d_out, int out_size, void* d_ws, size_t ws_size,
                              hipStream_t stream)
{
    const float* x     = (const float*)d_in[0];
    const float* w     = (const float*)d_in[1];
    const float* cb    = (const float*)d_in[2];
    const float* gamma = (const float*)d_in[3];
    const float* beta  = (const float*)d_in[4];
    const float* rm    = (const float*)d_in[5];
    const float* rv    = (const float*)d_in[6];
    const float* att0  = (const float*)d_in[7];
    float* out = (float*)d_out;
    unsigned short* y = (unsigned short*)d_ws;   // 2048*7168*2 = 29.4 MB padded bf16

    dim3 gA(TV / 128, 16);   // 50 x 16
    conv_mfma<<<gA, 256, 0, stream>>>(x, w, cb, gamma, beta, rm, rv, y);

    dim3 gB(16 * COUT);
    attn_kernel<<<gB, 256, 0, stream>>>(y, att0, out);
}

// Round 17
// 44.571 us; speedup vs baseline: 5.0021x; 5.0021x over previous
//
#include <hip/hip_runtime.h>
#include <hip/hip_bf16.h>

#define CIN   64
#define COUT  128
#define TT    256
#define VV    25
#define TV    (TT * VV)   // 6400
#define KW    9
#define PAD   4

typedef __attribute__((ext_vector_type(8))) short short8;   // 8 bf16 (4 VGPRs)
typedef __attribute__((ext_vector_type(4))) float f32x4;

__device__ __forceinline__ unsigned f2b(float f) {          // fp32 -> bf16 bits (RNE)
    unsigned u = __builtin_bit_cast(unsigned, f);
    return (u + 0x7FFFu + ((u >> 16) & 1u)) >> 16;
}
__device__ __forceinline__ float lof(unsigned u) {          // low bf16 -> f32
    return __builtin_bit_cast(float, u << 16);
}
__device__ __forceinline__ float hif(unsigned u) {          // high bf16 -> f32
    return __builtin_bit_cast(float, u & 0xffff0000u);
}
// conv LDS tile swizzle: [row][128B], XOR slot with (row&7)
__device__ __forceinline__ int swz(int row, int cbyte) {
    return row * 128 + ((cbyte & ~15) ^ ((row & 7) << 4)) + (cbyte & 15);
}

// ---------------- Kernel A: 1x1 conv + BN via bf16 MFMA ----------------
// grid (50 pos-chunks, 16 n); block 256 = 4 waves.
// OPERAND-SWAPPED vs R3..R15: A = X fragment (M = pos), B = W fragment (N = o).
// D layout (m89): reg-dim = pos (4 consecutive), lane&15-dim = channel ->
// each lane packs 4 consecutive pos of one channel = one uint2 store.
// y layout: UNPADDED [nc][6400] bf16. Epilogue: 16 uint2 stores, 0 divisions.
__global__ __launch_bounds__(256) void conv_mfma(
    const float* __restrict__ x, const float* __restrict__ w,
    const float* __restrict__ cb, const float* __restrict__ gamma,
    const float* __restrict__ beta, const float* __restrict__ rm,
    const float* __restrict__ rv, unsigned short* __restrict__ y)
{
    __shared__ __align__(16) unsigned short Wl[COUT * 64];   // 16 KB, swizzled
    __shared__ __align__(16) unsigned short Xl[128 * 64];    // 16 KB, swizzled [pos][c]
    __shared__ float sc[COUT];
    __shared__ float of[COUT];

    const int pc  = blockIdx.x;       // 0..49
    const int n   = blockIdx.y;       // 0..15
    const int tid = threadIdx.x;
    const int posbase = pc * 128;

    if (tid < COUT) {
        const float s = gamma[tid] * rsqrtf(rv[tid] + 1e-5f);
        sc[tid] = s;
        of[tid] = cb[tid] * s + beta[tid] - rm[tid] * s;
    }
    for (int idx = tid; idx < 2048; idx += 256) {
        const int c4 = idx & 15, o = idx >> 4;
        const f32x4 wv = *(const f32x4*)(w + o * 64 + c4 * 4);
        uint2 pk;
        pk.x = f2b(wv.x) | (f2b(wv.y) << 16);
        pk.y = f2b(wv.z) | (f2b(wv.w) << 16);
        *(uint2*)((char*)Wl + swz(o, c4 * 8)) = pk;
    }
    for (int idx = tid; idx < 2048; idx += 256) {
        const int pos = idx & 127, c4 = idx >> 7;
        const float* xp = x + (size_t)n * CIN * TV + (size_t)(c4 * 4) * TV + posbase + pos;
        const float a0 = xp[0], a1 = xp[TV], a2 = xp[2 * TV], a3 = xp[3 * TV];
        uint2 pk;
        pk.x = f2b(a0) | (f2b(a1) << 16);
        pk.y = f2b(a2) | (f2b(a3) << 16);
        *(uint2*)((char*)Xl + swz(pos, c4 * 8)) = pk;
    }
    __syncthreads();

    const int wv_ = tid >> 6, lane = tid & 63;
    const int lr = lane & 15, lh = lane >> 4;   // lh in 0..3

    // B fragments from W: rows o = wv_*32 + nn*16 + lr (loaded once)
    short8 bw[2][2];
#pragma unroll
    for (int nn = 0; nn < 2; ++nn)
#pragma unroll
        for (int kh = 0; kh < 2; ++kh)
            bw[nn][kh] = *(const short8*)((const char*)Wl +
                              swz(wv_ * 32 + nn * 16 + lr, kh * 64 + lh * 16));

    f32x4 acc[8][2];
#pragma unroll
    for (int m = 0; m < 8; ++m)
#pragma unroll
        for (int nn = 0; nn < 2; ++nn) acc[m][nn] = (f32x4){0.f, 0.f, 0.f, 0.f};

#pragma unroll
    for (int m = 0; m < 8; ++m) {
        const int prow = m * 16 + lr;
        const short8 a0 = *(const short8*)((const char*)Xl + swz(prow, lh * 16));
        const short8 a1 = *(const short8*)((const char*)Xl + swz(prow, 64 + lh * 16));
#pragma unroll
        for (int nn = 0; nn < 2; ++nn) {
            acc[m][nn] = __builtin_amdgcn_mfma_f32_16x16x32_bf16(a0, bw[nn][0], acc[m][nn], 0, 0, 0);
            acc[m][nn] = __builtin_amdgcn_mfma_f32_16x16x32_bf16(a1, bw[nn][1], acc[m][nn], 0, 0, 0);
        }
    }

    // epilogue: D[pos][o]: pos = m*16 + lh*4 + r, o = wv_*32 + nn*16 + lr
#pragma unroll
    for (int nn = 0; nn < 2; ++nn) {
        const int o = wv_ * 32 + nn * 16 + lr;
        const float s = sc[o], f = of[o];
        unsigned short* yb = y + (size_t)(n * COUT + o) * TV + posbase + lh * 4;
#pragma unroll
        for (int m = 0; m < 8; ++m) {
            const f32x4 a = acc[m][nn];
            uint2 pk;
            pk.x = f2b(a[0] * s + f) | (f2b(a[1] * s + f) << 16);
            pk.y = f2b(a[2] * s + f) | (f2b(a[3] * s + f) << 16);
            *(uint2*)(yb + m * 16) = pk;   // 8B-aligned: posbase+lh*4+m*16 ≡ 0 mod 4
        }
    }
}

// ---------------- Kernel B: temporal-window attention (R10 + repad staging) ----------------
// 2048 blocks x 256 threads, t = tid. Tile rows = 28 shorts (56B), halo 4 rows
// each side — IDENTICAL to R10 downstream (lane->row stride 1: 14*l mod 32
// sweeps all 16 evens -> conflict-free). Staging changed: y is unpadded
// [nc][6400], thread t re-pads its own row (14 dword loads + uniform
// alignbit/cndmask for odd t).
#define LOADROW(lr_, dst)                                                   \
    {                                                                       \
        const int ub_ = 7 * (lr_);                                          \
        const uint2 r0_ = tl2[ub_],     r1_ = tl2[ub_ + 1];                 \
        const uint2 r2_ = tl2[ub_ + 2], r3_ = tl2[ub_ + 3];                 \
        const uint2 r4_ = tl2[ub_ + 4], r5_ = tl2[ub_ + 5];                 \
        const unsigned l_ = tlu[14 * (lr_) + 12];                           \
        (dst)[0]  = lof(r0_.x); (dst)[1]  = hif(r0_.x);                     \
        (dst)[2]  = lof(r0_.y); (dst)[3]  = hif(r0_.y);                     \
        (dst)[4]  = lof(r1_.x); (dst)[5]  = hif(r1_.x);                     \
        (dst)[6]  = lof(r1_.y); (dst)[7]  = hif(r1_.y);                     \
        (dst)[8]  = lof(r2_.x); (dst)[9]  = hif(r2_.x);                     \
        (dst)[10] = lof(r2_.y); (dst)[11] = hif(r2_.y);                     \
        (dst)[12] = lof(r3_.x); (dst)[13] = hif(r3_.x);                     \
        (dst)[14] = lof(r3_.y); (dst)[15] = hif(r3_.y);                     \
        (dst)[16] = lof(r4_.x); (dst)[17] = hif(r4_.x);                     \
        (dst)[18] = lof(r4_.y); (dst)[19] = hif(r4_.y);                     \
        (dst)[20] = lof(r5_.x); (dst)[21] = hif(r5_.x);                     \
        (dst)[22] = lof(r5_.y); (dst)[23] = hif(r5_.y);                     \
        (dst)[24] = lof(l_);                                                \
    }

__global__ __launch_bounds__(256) void attn_kernel(
    const unsigned short* __restrict__ y, const float* __restrict__ att0,
    float* __restrict__ out)
{
    __shared__ __align__(16) float sm[TV];   // 25.6 KB: bf16 tile (14.8KB), then fp32 overlay
    __shared__ float a0s[KW];

    uint4* tl4 = (uint4*)sm;                  // tile: 924 uint4 = 14784 B
    const uint2* tl2 = (const uint2*)sm;
    const unsigned* tlu = (const unsigned*)sm;
    unsigned* tlw = (unsigned*)sm;

    const int nc  = blockIdx.x;       // n*COUT + c
    const int c   = nc & (COUT - 1);
    const int tid = threadIdx.x;

    if (tid < KW) a0s[tid] = att0[c * KW + tid];

    // zero halo: front uint4 [0,14) (rows -4..-1), back [910,924) (rows 256..259)
    if (tid < 28) {
        const int i = (tid < 14) ? tid : (896 + tid);
        tl4[i] = make_uint4(0, 0, 0, 0);
    }

    // stage: thread t re-pads row t (25 shorts -> 28-short tile row).
    // global short g = 25t + 2d (d=0..12): src dword s = g>>1, parity = t&1.
    {
        const unsigned* ygu = (const unsigned*)(y + (size_t)nc * TV);  // 3200 dwords
        const int t = tid;
        const int s0 = (25 * t) >> 1;
        const int odd = t & 1;
        unsigned u[14];
#pragma unroll
        for (int i = 0; i < 14; ++i) u[i] = ygu[min(s0 + i, 3199)];
        unsigned* dst = tlw + 14 * (t + 4);
#pragma unroll
        for (int d = 0; d < 13; ++d) {
            const unsigned shifted = (u[d] >> 16) | (u[d + 1] << 16);
            dst[d] = odd ? shifted : u[d];
        }
    }
    __syncthreads();

    const int t = tid;                // local center row = t + 4

    float q[25];
    LOADROW(t + 4, q);

    float osm[25], oa0[25];
    float den;
    {   // j = 4: self term (row == q, no LDS read)
        float d0 = 0.f, d1 = 0.f;
#pragma unroll
        for (int v = 0; v < 12; ++v)  d0 = fmaf(q[v], q[v], d0);
#pragma unroll
        for (int v = 12; v < 25; ++v) d1 = fmaf(q[v], q[v], d1);
        const float e = __expf((d0 + d1) * (1.f / 25.f));
        den = e;
        const float a = a0s[4];
#pragma unroll
        for (int v = 0; v < 25; ++v) { osm[v] = e * q[v]; oa0[v] = a * q[v]; }
    }

#pragma unroll
    for (int j = 0; j < KW; ++j) {
        if (j == 4) continue;
        float row[25];
        LOADROW(t + j, row);
        float d0 = 0.f, d1 = 0.f;
#pragma unroll
        for (int v = 0; v < 12; ++v)  d0 = fmaf(row[v], q[v], d0);
#pragma unroll
        for (int v = 12; v < 25; ++v) d1 = fmaf(row[v], q[v], d1);
        const float e = __expf((d0 + d1) * (1.f / 25.f));
        den += e;
        const float a = a0s[j];
#pragma unroll
        for (int v = 0; v < 25; ++v) {
            osm[v] = fmaf(e, row[v], osm[v]);
            oa0[v] = fmaf(a, row[v], oa0[v]);
        }
    }

    const float inv = 1.f / den;

    // ---- overlay pack (scalar b32; lane stride 25 dwords, odd -> benign) ----
    __syncthreads();
    {
        float* dst = &sm[t * 25];
#pragma unroll
        for (int v = 0; v < 25; ++v) dst[v] = fmaf(osm[v], inv, oa0[v]);
    }
    __syncthreads();

    // ---- block-contiguous float4 stores: full 64B lines per instruction ----
    {
        float4* og = (float4*)(out + (size_t)nc * TV);
        const float4* sm4 = (const float4*)sm;
#pragma unroll
        for (int i = 0; i < 7; ++i) {
            const int ci = tid + i * 256;
            if (ci < TV / 4) og[ci] = sm4[ci];
        }
    }
}

extern "C" void kernel_launch(void* const* d_in, const int* in_sizes, int n_in,
                              void* d_out, int out_size, void* d_ws, size_t ws_size,
                              hipStream_t stream)
{
    const float* x     = (const float*)d_in[0];
    const float* w     = (const float*)d_in[1];
    const float* cb    = (const float*)d_in[2];
    const float* gamma = (const float*)d_in[3];
    const float* beta  = (const float*)d_in[4];
    const float* rm    = (const float*)d_in[5];
    const float* rv    = (const float*)d_in[6];
    const float* att0  = (const float*)d_in[7];
    float* out = (float*)d_out;
    unsigned short* y = (unsigned short*)d_ws;   // 2048*6400*2 = 26.2 MB unpadded bf16

    dim3 gA(TV / 128, 16);   // 50 x 16
    conv_mfma<<<gA, 256, 0, stream>>>(x, w, cb, gamma, beta, rm, rv, y);

    dim3 gB(16 * COUT);
    attn_kernel<<<gB, 256, 0, stream>>>(y, att0, out);
}